// Round 10
// baseline (437.945 us; speedup 1.0000x reference)
//
#include <hip/hip_runtime.h>

#define IMG_W 1024
#define BATCH 32

// Fused, interleaved grid of 2560 blocks x 1024 threads:
//   bid % 5 == 0 -> Y block (512 total): height cumsum (channel 1),
//                   64 columns (32 float2 lanes) x full height, 32 segments.
//   else         -> X block (2048 total): width cumsum (channel 0),
//                   16 rows, one wave per row, contiguous float4 chunks.
// Interleaving keeps both access patterns co-resident (no Y-phase/X-phase).
__global__ __launch_bounds__(1024) void sgi_fused_kernel(const float* __restrict__ in,
                                                         float* __restrict__ out) {
    __shared__ float2 aux[32 * 32];   // Y-branch segment totals (8 KiB)

    const int bid = blockIdx.x;

    if (bid % 5 == 0) {
        // ------------------- Y: cumsum along height (channel 1) -------------
        // Thread (c = float2-column, s = segment of 32 rows). Per load/store
        // instruction a half-wave touches 256 B contiguous (2 x 256B bursts
        // per wave) -> half the VMEM instructions of the float1 version with
        // the same 256 KiB/block in-flight bytes.
        const int ybid = bid / 5;            // 0..511
        const int c = threadIdx.x & 31;      // float2 column within block
        const int s = threadIdx.x >> 5;      // segment (0..31)

        const int col2 = ybid * 32 + c;      // global float2 column, 0..16383
        const int b    = col2 >> 9;          // 512 float2 per image row
        const int x2   = col2 & 511;

        const size_t base = (size_t)b * (2 * IMG_W * IMG_W) + (size_t)(IMG_W * IMG_W)
                          + (size_t)x2 * 2 + (size_t)(s * 32) * IMG_W;

        const float2* ip = (const float2*)(in + base);
        float2*       op = (float2*)(out + base);
        const int rstride = IMG_W / 2;       // row stride in float2 units

        float2 v[32];
        float2 acc = make_float2(0.0f, 0.0f);
        #pragma unroll
        for (int i = 0; i < 32; ++i) {
            const float2 t = ip[(size_t)i * rstride];
            acc.x += t.x; acc.y += t.y;
            v[i] = acc;
        }

        aux[s * 32 + c] = acc;
        __syncthreads();

        // Exclusive prefix of segment totals for this column pair. Rows of
        // aux are broadcast across half-waves (identical addresses).
        float2 off = make_float2(0.0f, 0.0f);
        #pragma unroll
        for (int t = 0; t < 31; ++t) {
            const float2 tv = aux[t * 32 + c];
            const bool p = (t < s);
            off.x += p ? tv.x : 0.0f;
            off.y += p ? tv.y : 0.0f;
        }

        #pragma unroll
        for (int i = 0; i < 32; ++i) {
            float2 r;
            r.x = v[i].x + off.x;
            r.y = v[i].y + off.y;
            op[(size_t)i * rstride] = r;
        }
    } else {
        // ------------------- X: cumsum along width (channel 0) --------------
        // One wave per row. Row = 4 chunks of 256 floats; lane l loads
        // float4 #l of the chunk (1 KiB/instruction, perfectly coalesced).
        const int xbid = bid - bid / 5 - 1;              // 0..2047
        const int lane = threadIdx.x & 63;
        const int wave = threadIdx.x >> 6;
        const int row  = xbid * 16 + wave;               // 0 .. BATCH*IMG_W-1
        const int b    = row >> 10;
        const int y    = row & (IMG_W - 1);

        const size_t base = (size_t)b * (2 * IMG_W * IMG_W) + (size_t)y * IMG_W;
        const float4* ip = (const float4*)(in + base);
        float4*       op = (float4*)(out + base);

        // Hoist all 4 chunk loads (independent of the carry chain).
        float4 a[4];
        #pragma unroll
        for (int q = 0; q < 4; ++q) a[q] = ip[q * 64 + lane];

        float carry = 0.0f;
        #pragma unroll
        for (int q = 0; q < 4; ++q) {
            float4 v = a[q];
            v.y += v.x; v.z += v.y; v.w += v.z;          // local inclusive scan
            const float tot = v.w;
            float sfull = tot;
            #pragma unroll
            for (int d = 1; d < 64; d <<= 1) {           // wave scan of totals
                float n = __shfl_up(sfull, d);
                if (lane >= d) sfull += n;
            }
            const float add = (sfull - tot) + carry;     // exclusive prefix + carry
            v.x += add; v.y += add; v.z += add; v.w += add;
            op[q * 64 + lane] = v;
            carry += __shfl(sfull, 63);                  // chunk total broadcast
        }
    }
}

extern "C" void kernel_launch(void* const* d_in, const int* in_sizes, int n_in,
                              void* d_out, int out_size, void* d_ws, size_t ws_size,
                              hipStream_t stream) {
    const float* in  = (const float*)d_in[0];
    float*       out = (float*)d_out;

    // 512 Y blocks + 2048 X blocks, interleaved 1:4.
    sgi_fused_kernel<<<dim3(2560), dim3(1024), 0, stream>>>(in, out);
}